// Round 1
// baseline (591.316 us; speedup 1.0000x reference)
//
#include <hip/hip_runtime.h>

// Problem constants: B=4, C=32, D=H=W=64, N(fuzzy)=4
constexpr int Cc = 32;
constexpr int SP = 64 * 64 * 64;   // 262144 spatial per batch
constexpr int TS = 4 * SP;         // 1048576 total spatial (B*D*H*W)

// Workspace layout (floats):
//   [0, TS)        fuzz buffer (4 MiB)
//   acc = ws + TS:
//     acc[0], acc[1]        : bn1 sum, sumsq
//     acc[2], acc[3]        : bn1 scale a, shift c
//     acc[4..36)            : bn2 per-channel sum
//     acc[36..68)           : bn2 per-channel sumsq
//     acc[68..100)          : bn2 per-channel scale
//     acc[100..132)         : bn2 per-channel shift

// ---------------- Kernel 1: conv1 (32ch -> 1ch, 3x3x3 SAME) + fuzzy + bn1 stats
// 4x z-register-blocking: each thread produces outputs z0..z0+3 at fixed (b,y,w).
// Loads per output drop 864 -> 432 (rows reused across dz taps).
__global__ __launch_bounds__(256) void k_conv1_fuzzy(
    const float* __restrict__ x, const float* __restrict__ w1,
    const float* __restrict__ b1, const float* __restrict__ mu,
    const float* __restrict__ sg, float* __restrict__ fuzz,
    float* __restrict__ acc)
{
    const int tid = threadIdx.x;
    const int p = blockIdx.x * 256 + tid;        // over TS/4 = 262144
    const int w  = p & 63;
    const int y  = (p >> 6) & 63;
    const int z0 = ((p >> 12) & 15) * 4;
    const int b  = p >> 16;

    // fuzzy coefficients (wave-uniform scalar math): sum_n ((t-m)/s)^2 = S1*t^2 - 2*S2*t + S3
    float S1 = 0.f, S2 = 0.f, S3 = 0.f;
#pragma unroll
    for (int n = 0; n < 4; n++) {
        float m = mu[n], s = sg[n];
        float iv = 1.0f / (s * s);
        S1 += iv; S2 += m * iv; S3 += m * m * iv;
    }

    const bool wl = (w > 0), wr = (w < 63);
    float a0, a1, a2, a3;
    a0 = a1 = a2 = a3 = b1[0];

    const float* xb = x + (size_t)b * Cc * SP;
    for (int c = 0; c < Cc; c++) {
        const float* xc = xb + c * SP;
        const float* wc = w1 + c * 27;           // layout (1,C,3,3,3)
#pragma unroll
        for (int rel = 0; rel < 6; rel++) {      // zz = z0-1 .. z0+4
            int zz = z0 + rel - 1;
            if (zz < 0 || zz > 63) continue;     // wave-uniform branch
            const float* xz = xc + (zz << 12);
#pragma unroll
            for (int dy = 0; dy < 3; dy++) {
                int yy = y + dy - 1;
                if ((unsigned)yy > 63u) continue;  // wave-uniform branch
                const float* row = xz + (yy << 6) + w;
                float vm = row[0];
                float vl = 0.f, vr = 0.f;
                if (wl) vl = row[-1];
                if (wr) vr = row[1];
#pragma unroll
                for (int oz = 0; oz < 4; oz++) { // which output this row feeds
                    const int dz = rel - oz;     // compile-time after unroll
                    if (dz < 0 || dz > 2) continue;
                    const float* wp = wc + (dz * 3 + dy) * 3;
                    float part = vl * wp[0] + vm * wp[1] + vr * wp[2];
                    if      (oz == 0) a0 += part;
                    else if (oz == 1) a1 += part;
                    else if (oz == 2) a2 += part;
                    else              a3 += part;
                }
            }
        }
    }

    float fsum = 0.f, fsq = 0.f;
#pragma unroll
    for (int oz = 0; oz < 4; oz++) {
        float x1 = (oz == 0) ? a0 : (oz == 1) ? a1 : (oz == 2) ? a2 : a3;
        float t  = x1 * x1 * S1 - 2.0f * x1 * S2 + S3;
        float fz = __expf(-t);
        fuzz[((size_t)((b * 64 + z0 + oz) * 64 + y) << 6) + w] = fz;
        fsum += fz; fsq += fz * fz;
    }

    // wave(64) butterfly + cross-wave LDS + one atomic pair per block
#pragma unroll
    for (int m = 1; m < 64; m <<= 1) {
        fsum += __shfl_xor(fsum, m, 64);
        fsq  += __shfl_xor(fsq,  m, 64);
    }
    __shared__ float red[8];
    int lane = tid & 63, wid = tid >> 6;
    if (lane == 0) { red[wid * 2] = fsum; red[wid * 2 + 1] = fsq; }
    __syncthreads();
    if (tid == 0) {
        atomicAdd(&acc[0], red[0] + red[2] + red[4] + red[6]);
        atomicAdd(&acc[1], red[1] + red[3] + red[5] + red[7]);
    }
}

// ---------------- Kernel 2: finalize bn1 -> affine (a, c)
__global__ void k_fin1(const float* __restrict__ g, const float* __restrict__ be,
                       float* __restrict__ acc)
{
    float mean = acc[0] * (1.0f / TS);
    float var  = acc[1] * (1.0f / TS) - mean * mean;
    float a = g[0] * rsqrtf(var + 1e-5f);
    acc[2] = a;
    acc[3] = be[0] - mean * a;
}

// ---------------- Kernel 3: conv2 (1ch -> 32ch, 3x3x3 SAME), bn1 affine folded into loads
// One thread per spatial position computes all 32 channels: 27 neighborhood loads,
// weights fetched via wave-uniform scalar loads (SMEM pipe).
__global__ __launch_bounds__(256) void k_conv2(
    const float* __restrict__ fuzz, const float* __restrict__ w2,
    const float* __restrict__ b2, const float* __restrict__ acc,
    float* __restrict__ out)
{
    const int p = blockIdx.x * 256 + threadIdx.x;   // over TS
    const int w = p & 63, y = (p >> 6) & 63, z = (p >> 12) & 63, b = p >> 18;
    const float a = acc[2], sh = acc[3];
    const bool wl = (w > 0), wr = (w < 63);
    const float* fb = fuzz + (size_t)b * SP;

    float v[27];
#pragma unroll
    for (int dz = 0; dz < 3; dz++) {
        int zz = z + dz - 1;
        bool mz = (unsigned)zz < 64u;               // wave-uniform
#pragma unroll
        for (int dy = 0; dy < 3; dy++) {
            int yy = y + dy - 1;
            bool my = (unsigned)yy < 64u;           // wave-uniform
            int i = (dz * 3 + dy) * 3;
            float vl = 0.f, vm = 0.f, vr = 0.f;
            if (mz && my) {
                const float* row = fb + (zz << 12) + (yy << 6) + w;
                vm = fmaf(a, row[0], sh);           // bn1 affine; SAME-pad stays 0
                if (wl) vl = fmaf(a, row[-1], sh);
                if (wr) vr = fmaf(a, row[1], sh);
            }
            v[i] = vl; v[i + 1] = vm; v[i + 2] = vr;
        }
    }

    float* ob = out + (size_t)b * Cc * SP + (p - b * SP);
#pragma unroll 4
    for (int c = 0; c < Cc; c++) {
        const float* wc = w2 + c * 27;              // layout (C,1,3,3,3)
        float o = b2[c];
#pragma unroll
        for (int j = 0; j < 27; j++) o = fmaf(v[j], wc[j], o);
        ob[(size_t)c * SP] = o;
    }
}

// ---------------- Kernel 4: per-channel sum/sumsq over conv2 output
// grid = B*C*32 = 4096 blocks; each block reduces 8192 contiguous elems of one channel slab.
__global__ __launch_bounds__(256) void k_stats2(const float4* __restrict__ out4,
                                                float* __restrict__ acc)
{
    int blk = blockIdx.x;                 // b*1024 + c*32 + seg
    int c = (blk >> 5) & 31;
    const float4* pp = out4 + (size_t)blk * 2048 + threadIdx.x;
    float s = 0.f, q = 0.f;
#pragma unroll
    for (int i = 0; i < 8; i++) {
        float4 v = pp[i * 256];
        s += v.x + v.y + v.z + v.w;
        q += v.x * v.x + v.y * v.y + v.z * v.z + v.w * v.w;
    }
#pragma unroll
    for (int m = 1; m < 64; m <<= 1) {
        s += __shfl_xor(s, m, 64);
        q += __shfl_xor(q, m, 64);
    }
    __shared__ float red[8];
    int lane = threadIdx.x & 63, wid = threadIdx.x >> 6;
    if (lane == 0) { red[wid * 2] = s; red[wid * 2 + 1] = q; }
    __syncthreads();
    if (threadIdx.x == 0) {
        atomicAdd(&acc[4 + c],  red[0] + red[2] + red[4] + red[6]);
        atomicAdd(&acc[36 + c], red[1] + red[3] + red[5] + red[7]);
    }
}

// ---------------- Kernel 5: finalize bn2 -> per-channel scale/shift
__global__ void k_fin2(const float* __restrict__ g, const float* __restrict__ be,
                       float* __restrict__ acc)
{
    int c = threadIdx.x;                  // 32 threads
    float mean = acc[4 + c] * (1.0f / TS);
    float var  = acc[36 + c] * (1.0f / TS) - mean * mean;
    float sc = g[c] * rsqrtf(var + 1e-5f);
    acc[68 + c]  = sc;
    acc[100 + c] = be[c] - mean * sc;
}

// ---------------- Kernel 6: in-place normalize (float4 vectorized)
__global__ __launch_bounds__(256) void k_norm(float4* __restrict__ out4,
                                              const float* __restrict__ acc)
{
    size_t i = (size_t)blockIdx.x * 256 + threadIdx.x;   // 8388608 float4
    int c = (int)((i >> 16) & 31);                       // 65536 float4 per channel slab
    float sc = acc[68 + c], sh = acc[100 + c];
    float4 v = out4[i];
    v.x = fmaf(v.x, sc, sh);
    v.y = fmaf(v.y, sc, sh);
    v.z = fmaf(v.z, sc, sh);
    v.w = fmaf(v.w, sc, sh);
    out4[i] = v;
}

extern "C" void kernel_launch(void* const* d_in, const int* in_sizes, int n_in,
                              void* d_out, int out_size, void* d_ws, size_t ws_size,
                              hipStream_t stream)
{
    const float* x   = (const float*)d_in[0];
    const float* w1  = (const float*)d_in[1];
    const float* b1  = (const float*)d_in[2];
    const float* w2  = (const float*)d_in[3];
    const float* b2  = (const float*)d_in[4];
    const float* mu  = (const float*)d_in[5];
    const float* sg  = (const float*)d_in[6];
    const float* g1  = (const float*)d_in[7];
    const float* be1 = (const float*)d_in[8];
    const float* g2  = (const float*)d_in[9];
    const float* be2 = (const float*)d_in[10];

    float* out  = (float*)d_out;
    float* fuzz = (float*)d_ws;
    float* acc  = fuzz + TS;

    hipMemsetAsync(acc, 0, 132 * sizeof(float), stream);
    k_conv1_fuzzy<<<TS / 4 / 256, 256, 0, stream>>>(x, w1, b1, mu, sg, fuzz, acc);
    k_fin1<<<1, 1, 0, stream>>>(g1, be1, acc);
    k_conv2<<<TS / 256, 256, 0, stream>>>(fuzz, w2, b2, acc, out);
    k_stats2<<<4096, 256, 0, stream>>>((const float4*)out, acc);
    k_fin2<<<1, 32, 0, stream>>>(g2, be2, acc);
    k_norm<<<32768, 256, 0, stream>>>((float4*)out, acc);
}

// Round 2
// 439.907 us; speedup vs baseline: 1.3442x; 1.3442x over previous
//
#include <hip/hip_runtime.h>

// Problem constants: B=4, C=32, D=H=W=64, N(fuzzy)=4
constexpr int Cc = 32;
constexpr int SP = 64 * 64 * 64;   // 262144 spatial per batch
constexpr int TS = 4 * SP;         // 1048576 total spatial (B*D*H*W)

// Workspace layout (floats):
//   [0, TS)        fuzz buffer (4 MiB)
//   acc = ws + TS:
//     acc[0], acc[1]        : bn1 sum, sumsq
//     acc[2], acc[3]        : bn1 scale a, shift c
//     acc[4..36)            : bn2 per-channel sum
//     acc[36..68)           : bn2 per-channel sumsq
//     acc[68..100)          : bn2 per-channel scale
//     acc[100..132)         : bn2 per-channel shift

// ---------------- Kernel 1: conv1 (32ch -> 1ch, 3x3x3 SAME) + fuzzy + bn1 stats
// Register tile: w x4 (float4 loads), z x2. 8 outputs/thread.
// Per channel: 12 aligned float4 row loads (batched, independent, coalesced
// 256B/16-lane segment); w-halo via __shfl from adjacent lane (no unaligned
// scalar gathers); 216 FMAs vs wave-uniform scalar weights.
__global__ __launch_bounds__(256) void k_conv1_fuzzy(
    const float* __restrict__ x, const float* __restrict__ w1,
    const float* __restrict__ b1, const float* __restrict__ mu,
    const float* __restrict__ sg, float* __restrict__ fuzz,
    float* __restrict__ acc)
{
    const int tid = threadIdx.x;
    const int t = blockIdx.x * 256 + tid;        // 131072 threads total
    const int wq = t & 15;        const int w0 = wq << 2;   // w quad
    const int zp = (t >> 4) & 31; const int z0 = zp << 1;   // z pair
    const int y  = (t >> 9) & 63;
    const int b  = t >> 15;
    const int lane = tid & 63;

    // fuzzy coefficients: sum_n ((t-m)/s)^2 = S1*t^2 - 2*S2*t + S3
    float S1 = 0.f, S2 = 0.f, S3 = 0.f;
#pragma unroll
    for (int n = 0; n < 4; n++) {
        float m = mu[n], s = sg[n];
        float iv = 1.0f / (s * s);
        S1 += iv; S2 += m * iv; S3 += m * m * iv;
    }

    const float b1v = b1[0];
    float a00 = b1v, a01 = b1v, a02 = b1v, a03 = b1v;  // oz=0, ow=0..3
    float a10 = b1v, a11 = b1v, a12 = b1v, a13 = b1v;  // oz=1

    const float* xb = x + (size_t)b * Cc * SP;

    for (int c = 0; c < Cc; c++) {
        const float* xc = xb + c * SP;
        const float* wc = w1 + c * 27;           // (1,C,3,3,3): uniform scalar loads

        // ---- load 12 rows (4 zz x 3 dy), all independent -> deep VMEM batch
        float4 M[4][3];
#pragma unroll
        for (int rz = 0; rz < 4; rz++) {
            const int zz = z0 - 1 + rz;
            const bool okz = (unsigned)zz < 64u;
#pragma unroll
            for (int dy = 0; dy < 3; dy++) {
                const int yy = y - 1 + dy;
                float4 m = make_float4(0.f, 0.f, 0.f, 0.f);
                if (okz && (unsigned)yy < 64u)
                    m = *(const float4*)(xc + (zz << 12) + (yy << 6) + w0);
                M[rz][dy] = m;
            }
        }

        // ---- w-halo via cross-lane shuffle (lane-1 holds w0-4..w0-1, etc.)
        float L[4][3], R[4][3];
#pragma unroll
        for (int rz = 0; rz < 4; rz++)
#pragma unroll
            for (int dy = 0; dy < 3; dy++) {
                float lv = __shfl(M[rz][dy].w, (lane + 63) & 63, 64);
                float rv = __shfl(M[rz][dy].x, (lane + 1) & 63, 64);
                L[rz][dy] = (wq > 0)  ? lv : 0.f;   // SAME pad at w=0
                R[rz][dy] = (wq < 15) ? rv : 0.f;   // SAME pad at w=63
            }

        // ---- FMAs: row (rz,dy) feeds output oz where dz = rz-oz in [0,2]
#pragma unroll
        for (int rz = 0; rz < 4; rz++) {
#pragma unroll
            for (int dy = 0; dy < 3; dy++) {
                const float v0 = L[rz][dy];
                const float v1 = M[rz][dy].x, v2 = M[rz][dy].y;
                const float v3 = M[rz][dy].z, v4 = M[rz][dy].w;
                const float v5 = R[rz][dy];
                if (rz < 3) {                        // oz=0, dz=rz
                    const float* wr = wc + (rz * 3 + dy) * 3;
                    const float W0 = wr[0], W1 = wr[1], W2 = wr[2];
                    a00 = fmaf(v0, W0, fmaf(v1, W1, fmaf(v2, W2, a00)));
                    a01 = fmaf(v1, W0, fmaf(v2, W1, fmaf(v3, W2, a01)));
                    a02 = fmaf(v2, W0, fmaf(v3, W1, fmaf(v4, W2, a02)));
                    a03 = fmaf(v3, W0, fmaf(v4, W1, fmaf(v5, W2, a03)));
                }
                if (rz >= 1) {                       // oz=1, dz=rz-1
                    const float* wr = wc + ((rz - 1) * 3 + dy) * 3;
                    const float W0 = wr[0], W1 = wr[1], W2 = wr[2];
                    a10 = fmaf(v0, W0, fmaf(v1, W1, fmaf(v2, W2, a10)));
                    a11 = fmaf(v1, W0, fmaf(v2, W1, fmaf(v3, W2, a11)));
                    a12 = fmaf(v2, W0, fmaf(v3, W1, fmaf(v4, W2, a12)));
                    a13 = fmaf(v3, W0, fmaf(v4, W1, fmaf(v5, W2, a13)));
                }
            }
        }
    }

    // ---- fuzzy membership + store (float4, coalesced) + bn1 stats
    float fsum = 0.f, fsq = 0.f;
#pragma unroll
    for (int oz = 0; oz < 2; oz++) {
        float xv[4] = { oz ? a10 : a00, oz ? a11 : a01,
                        oz ? a12 : a02, oz ? a13 : a03 };
        float4 fv;
        float* fp = &fv.x;
#pragma unroll
        for (int ow = 0; ow < 4; ow++) {
            float x1 = xv[ow];
            float tt = x1 * x1 * S1 - 2.0f * x1 * S2 + S3;
            float fz = __expf(-tt);
            fp[ow] = fz;
            fsum += fz; fsq += fz * fz;
        }
        *(float4*)(fuzz + (size_t)b * SP + ((z0 + oz) << 12) + (y << 6) + w0) = fv;
    }

    // wave(64) butterfly + cross-wave LDS + one atomic pair per block
#pragma unroll
    for (int m = 1; m < 64; m <<= 1) {
        fsum += __shfl_xor(fsum, m, 64);
        fsq  += __shfl_xor(fsq,  m, 64);
    }
    __shared__ float red[8];
    int wid = tid >> 6;
    if ((tid & 63) == 0) { red[wid * 2] = fsum; red[wid * 2 + 1] = fsq; }
    __syncthreads();
    if (tid == 0) {
        atomicAdd(&acc[0], red[0] + red[2] + red[4] + red[6]);
        atomicAdd(&acc[1], red[1] + red[3] + red[5] + red[7]);
    }
}

// ---------------- Kernel 2: finalize bn1 -> affine (a, c)
__global__ void k_fin1(const float* __restrict__ g, const float* __restrict__ be,
                       float* __restrict__ acc)
{
    float mean = acc[0] * (1.0f / TS);
    float var  = acc[1] * (1.0f / TS) - mean * mean;
    float a = g[0] * rsqrtf(var + 1e-5f);
    acc[2] = a;
    acc[3] = be[0] - mean * a;
}

// ---------------- Kernel 3: conv2 (1ch -> 32ch, 3x3x3 SAME), bn1 affine folded into loads
__global__ __launch_bounds__(256) void k_conv2(
    const float* __restrict__ fuzz, const float* __restrict__ w2,
    const float* __restrict__ b2, const float* __restrict__ acc,
    float* __restrict__ out)
{
    const int p = blockIdx.x * 256 + threadIdx.x;   // over TS
    const int w = p & 63, y = (p >> 6) & 63, z = (p >> 12) & 63, b = p >> 18;
    const float a = acc[2], sh = acc[3];
    const bool wl = (w > 0), wr = (w < 63);
    const float* fb = fuzz + (size_t)b * SP;

    float v[27];
#pragma unroll
    for (int dz = 0; dz < 3; dz++) {
        int zz = z + dz - 1;
        bool mz = (unsigned)zz < 64u;
#pragma unroll
        for (int dy = 0; dy < 3; dy++) {
            int yy = y + dy - 1;
            bool my = (unsigned)yy < 64u;
            int i = (dz * 3 + dy) * 3;
            float vl = 0.f, vm = 0.f, vr = 0.f;
            if (mz && my) {
                const float* row = fb + (zz << 12) + (yy << 6) + w;
                vm = fmaf(a, row[0], sh);           // bn1 affine; SAME-pad stays 0
                if (wl) vl = fmaf(a, row[-1], sh);
                if (wr) vr = fmaf(a, row[1], sh);
            }
            v[i] = vl; v[i + 1] = vm; v[i + 2] = vr;
        }
    }

    float* ob = out + (size_t)b * Cc * SP + (p - b * SP);
#pragma unroll 4
    for (int c = 0; c < Cc; c++) {
        const float* wc = w2 + c * 27;              // layout (C,1,3,3,3)
        float o = b2[c];
#pragma unroll
        for (int j = 0; j < 27; j++) o = fmaf(v[j], wc[j], o);
        ob[(size_t)c * SP] = o;
    }
}

// ---------------- Kernel 4: per-channel sum/sumsq over conv2 output
__global__ __launch_bounds__(256) void k_stats2(const float4* __restrict__ out4,
                                                float* __restrict__ acc)
{
    int blk = blockIdx.x;                 // b*1024 + c*32 + seg
    int c = (blk >> 5) & 31;
    const float4* pp = out4 + (size_t)blk * 2048 + threadIdx.x;
    float s = 0.f, q = 0.f;
#pragma unroll
    for (int i = 0; i < 8; i++) {
        float4 v = pp[i * 256];
        s += v.x + v.y + v.z + v.w;
        q += v.x * v.x + v.y * v.y + v.z * v.z + v.w * v.w;
    }
#pragma unroll
    for (int m = 1; m < 64; m <<= 1) {
        s += __shfl_xor(s, m, 64);
        q += __shfl_xor(q, m, 64);
    }
    __shared__ float red[8];
    int lane = threadIdx.x & 63, wid = threadIdx.x >> 6;
    if (lane == 0) { red[wid * 2] = s; red[wid * 2 + 1] = q; }
    __syncthreads();
    if (threadIdx.x == 0) {
        atomicAdd(&acc[4 + c],  red[0] + red[2] + red[4] + red[6]);
        atomicAdd(&acc[36 + c], red[1] + red[3] + red[5] + red[7]);
    }
}

// ---------------- Kernel 5: finalize bn2 -> per-channel scale/shift
__global__ void k_fin2(const float* __restrict__ g, const float* __restrict__ be,
                       float* __restrict__ acc)
{
    int c = threadIdx.x;                  // 32 threads
    float mean = acc[4 + c] * (1.0f / TS);
    float var  = acc[36 + c] * (1.0f / TS) - mean * mean;
    float sc = g[c] * rsqrtf(var + 1e-5f);
    acc[68 + c]  = sc;
    acc[100 + c] = be[c] - mean * sc;
}

// ---------------- Kernel 6: in-place normalize (float4 vectorized)
__global__ __launch_bounds__(256) void k_norm(float4* __restrict__ out4,
                                              const float* __restrict__ acc)
{
    size_t i = (size_t)blockIdx.x * 256 + threadIdx.x;   // 8388608 float4
    int c = (int)((i >> 16) & 31);                       // 65536 float4 per channel slab
    float sc = acc[68 + c], sh = acc[100 + c];
    float4 v = out4[i];
    v.x = fmaf(v.x, sc, sh);
    v.y = fmaf(v.y, sc, sh);
    v.z = fmaf(v.z, sc, sh);
    v.w = fmaf(v.w, sc, sh);
    out4[i] = v;
}

extern "C" void kernel_launch(void* const* d_in, const int* in_sizes, int n_in,
                              void* d_out, int out_size, void* d_ws, size_t ws_size,
                              hipStream_t stream)
{
    const float* x   = (const float*)d_in[0];
    const float* w1  = (const float*)d_in[1];
    const float* b1  = (const float*)d_in[2];
    const float* w2  = (const float*)d_in[3];
    const float* b2  = (const float*)d_in[4];
    const float* mu  = (const float*)d_in[5];
    const float* sg  = (const float*)d_in[6];
    const float* g1  = (const float*)d_in[7];
    const float* be1 = (const float*)d_in[8];
    const float* g2  = (const float*)d_in[9];
    const float* be2 = (const float*)d_in[10];

    float* out  = (float*)d_out;
    float* fuzz = (float*)d_ws;
    float* acc  = fuzz + TS;

    hipMemsetAsync(acc, 0, 132 * sizeof(float), stream);
    k_conv1_fuzzy<<<512, 256, 0, stream>>>(x, w1, b1, mu, sg, fuzz, acc);
    k_fin1<<<1, 1, 0, stream>>>(g1, be1, acc);
    k_conv2<<<TS / 256, 256, 0, stream>>>(fuzz, w2, b2, acc, out);
    k_stats2<<<4096, 256, 0, stream>>>((const float4*)out, acc);
    k_fin2<<<1, 32, 0, stream>>>(g2, be2, acc);
    k_norm<<<32768, 256, 0, stream>>>((float4*)out, acc);
}

// Round 3
// 414.132 us; speedup vs baseline: 1.4278x; 1.0622x over previous
//
#include <hip/hip_runtime.h>

// Problem constants: B=4, C=32, D=H=W=64, N(fuzzy)=4
constexpr int Cc = 32;
constexpr int SP = 64 * 64 * 64;   // 262144 spatial per batch
constexpr int TS = 4 * SP;         // 1048576 total spatial

// Workspace layout (floats):
//   [0, TS)  fuzz (4 MiB);  acc = ws+TS:
//   acc[0..2): bn1 sum,sumsq  acc[2..4): bn1 a,c
//   acc[4..36): bn2 sum/ch    acc[36..68): bn2 sumsq/ch
//   acc[68..100): bn2 scale   acc[100..132): bn2 shift

// ---------------- Kernel 1: conv1 (32->1, 3x3x3 SAME) + fuzzy + bn1 stats
// w x4 / z x2 register tile + software-pipelined channel loop (double-buffered
// 12x float4 prefetch of channel c+1 during the 216-FMA compute of channel c).
__global__ __launch_bounds__(256) void k_conv1_fuzzy(
    const float* __restrict__ x, const float* __restrict__ w1,
    const float* __restrict__ b1, const float* __restrict__ mu,
    const float* __restrict__ sg, float* __restrict__ fuzz,
    float* __restrict__ acc)
{
    const int tid = threadIdx.x;
    const int t = blockIdx.x * 256 + tid;        // 131072 threads
    const int wq = t & 15;        const int w0 = wq << 2;
    const int zp = (t >> 4) & 31; const int z0 = zp << 1;
    const int y  = (t >> 9) & 63;
    const int b  = t >> 15;
    const int lane = tid & 63;

    float S1 = 0.f, S2 = 0.f, S3 = 0.f;
#pragma unroll
    for (int n = 0; n < 4; n++) {
        float m = mu[n], s = sg[n];
        float iv = 1.0f / (s * s);
        S1 += iv; S2 += m * iv; S3 += m * m * iv;
    }

    const float b1v = b1[0];
    float a00 = b1v, a01 = b1v, a02 = b1v, a03 = b1v;
    float a10 = b1v, a11 = b1v, a12 = b1v, a13 = b1v;

    const float* xb = x + (size_t)b * Cc * SP;

    // channel-invariant row predicates + offsets
    bool pv[12]; int ofs[12];
#pragma unroll
    for (int rz = 0; rz < 4; rz++) {
        const int zz = z0 - 1 + rz;
        const bool okz = (unsigned)zz < 64u;
#pragma unroll
        for (int dy = 0; dy < 3; dy++) {
            const int yy = y - 1 + dy;
            pv[rz * 3 + dy]  = okz && ((unsigned)yy < 64u);
            ofs[rz * 3 + dy] = (zz << 12) + (yy << 6) + w0;
        }
    }

    auto LOADCH = [&](int c, float4 (&M)[12]) {
        const float* xc = xb + (size_t)c * SP;
#pragma unroll
        for (int i = 0; i < 12; i++)
            M[i] = pv[i] ? *(const float4*)(xc + ofs[i])
                         : make_float4(0.f, 0.f, 0.f, 0.f);
    };

    auto COMPUTECH = [&](int c, const float4 (&M)[12]) {
        const float* wc = w1 + c * 27;           // uniform -> s_load
        float Wv[27];
#pragma unroll
        for (int k = 0; k < 27; k++) Wv[k] = wc[k];
#pragma unroll
        for (int rz = 0; rz < 4; rz++) {
#pragma unroll
            for (int dy = 0; dy < 3; dy++) {
                const float4 m = M[rz * 3 + dy];
                const float lv = __shfl(m.w, (lane + 63) & 63, 64);
                const float rv = __shfl(m.x, (lane + 1) & 63, 64);
                const float v0 = (wq > 0)  ? lv : 0.f;
                const float v5 = (wq < 15) ? rv : 0.f;
                const float v1 = m.x, v2 = m.y, v3 = m.z, v4 = m.w;
                if (rz < 3) {
                    const float W0 = Wv[(rz*3+dy)*3], W1 = Wv[(rz*3+dy)*3+1], W2 = Wv[(rz*3+dy)*3+2];
                    a00 = fmaf(v0, W0, fmaf(v1, W1, fmaf(v2, W2, a00)));
                    a01 = fmaf(v1, W0, fmaf(v2, W1, fmaf(v3, W2, a01)));
                    a02 = fmaf(v2, W0, fmaf(v3, W1, fmaf(v4, W2, a02)));
                    a03 = fmaf(v3, W0, fmaf(v4, W1, fmaf(v5, W2, a03)));
                }
                if (rz >= 1) {
                    const float W0 = Wv[((rz-1)*3+dy)*3], W1 = Wv[((rz-1)*3+dy)*3+1], W2 = Wv[((rz-1)*3+dy)*3+2];
                    a10 = fmaf(v0, W0, fmaf(v1, W1, fmaf(v2, W2, a10)));
                    a11 = fmaf(v1, W0, fmaf(v2, W1, fmaf(v3, W2, a11)));
                    a12 = fmaf(v2, W0, fmaf(v3, W1, fmaf(v4, W2, a12)));
                    a13 = fmaf(v3, W0, fmaf(v4, W1, fmaf(v5, W2, a13)));
                }
            }
        }
    };

    float4 Ma[12], Mb[12];
    LOADCH(0, Ma);
    for (int c = 0; c < Cc; c += 2) {
        LOADCH(c + 1, Mb);                 // prefetch while computing c
        COMPUTECH(c, Ma);
        if (c + 2 < Cc) LOADCH(c + 2, Ma); // prefetch while computing c+1
        COMPUTECH(c + 1, Mb);
    }

    // fuzzy + store + bn1 stats
    float fsum = 0.f, fsq = 0.f;
#pragma unroll
    for (int oz = 0; oz < 2; oz++) {
        float xv[4] = { oz ? a10 : a00, oz ? a11 : a01,
                        oz ? a12 : a02, oz ? a13 : a03 };
        float4 fv; float* fp = &fv.x;
#pragma unroll
        for (int ow = 0; ow < 4; ow++) {
            float x1 = xv[ow];
            float tt = x1 * x1 * S1 - 2.0f * x1 * S2 + S3;
            float fz = __expf(-tt);
            fp[ow] = fz; fsum += fz; fsq += fz * fz;
        }
        *(float4*)(fuzz + (size_t)b * SP + ((z0 + oz) << 12) + (y << 6) + w0) = fv;
    }
#pragma unroll
    for (int m = 1; m < 64; m <<= 1) {
        fsum += __shfl_xor(fsum, m, 64);
        fsq  += __shfl_xor(fsq,  m, 64);
    }
    __shared__ float red[8];
    const int wid = tid >> 6;
    if ((tid & 63) == 0) { red[wid * 2] = fsum; red[wid * 2 + 1] = fsq; }
    __syncthreads();
    if (tid == 0) {
        atomicAdd(&acc[0], red[0] + red[2] + red[4] + red[6]);
        atomicAdd(&acc[1], red[1] + red[3] + red[5] + red[7]);
    }
}

// ---------------- Kernel 2: finalize bn1 -> affine (a, c)
__global__ void k_fin1(const float* __restrict__ g, const float* __restrict__ be,
                       float* __restrict__ acc)
{
    float mean = acc[0] * (1.0f / TS);
    float var  = acc[1] * (1.0f / TS) - mean * mean;
    float a = g[0] * rsqrtf(var + 1e-5f);
    acc[2] = a;
    acc[3] = be[0] - mean * a;
}

// ---------------- Kernel 3: conv2 STATS pass — no output write.
// z x4 per thread; per-channel wave butterfly -> LDS -> 64 atomics/block.
__global__ __launch_bounds__(256) void k_conv2_stats(
    const float* __restrict__ fuzz, const float* __restrict__ w2,
    const float* __restrict__ b2, float* __restrict__ acc)
{
    const int tid = threadIdx.x;
    const int t = blockIdx.x * 256 + tid;        // 262144 threads
    const int lane = tid & 63;
    const int w = t & 63;                        // == lane
    const int y = (t >> 6) & 63;
    const int z0 = ((t >> 12) & 15) << 2;
    const int b = t >> 16;
    const float a = acc[2], sh = acc[3];
    const float* fb = fuzz + (size_t)b * SP;

    float Fl[6][3], Fm[6][3], Fr[6][3];
#pragma unroll
    for (int rz = 0; rz < 6; rz++) {
        const int zz = z0 - 1 + rz;
        const bool okz = (unsigned)zz < 64u;
#pragma unroll
        for (int dy = 0; dy < 3; dy++) {
            const int yy = y - 1 + dy;
            float f = 0.f;
            if (okz && (unsigned)yy < 64u)
                f = fmaf(a, fb[(zz << 12) + (yy << 6) + w], sh);
            const float lv = __shfl(f, (lane + 63) & 63, 64);
            const float rv = __shfl(f, (lane + 1) & 63, 64);
            Fm[rz][dy] = f;
            Fl[rz][dy] = (w > 0)  ? lv : 0.f;
            Fr[rz][dy] = (w < 63) ? rv : 0.f;
        }
    }

    __shared__ float red[2][32][4];
    const int wid = tid >> 6;

#pragma unroll
    for (int c = 0; c < Cc; c++) {
        const float* wc = w2 + c * 27;
        float Wv[27];
#pragma unroll
        for (int k = 0; k < 27; k++) Wv[k] = wc[k];
        const float bb = b2[c];
        float o0 = bb, o1 = bb, o2 = bb, o3 = bb;
#pragma unroll
        for (int rz = 0; rz < 6; rz++) {
#pragma unroll
            for (int dy = 0; dy < 3; dy++) {
                const float l = Fl[rz][dy], m = Fm[rz][dy], r = Fr[rz][dy];
#pragma unroll
                for (int oz = 0; oz < 4; oz++) {
                    const int dz = rz - oz;
                    if (dz < 0 || dz > 2) continue;
                    const float W0 = Wv[(dz*3+dy)*3], W1 = Wv[(dz*3+dy)*3+1], W2 = Wv[(dz*3+dy)*3+2];
                    if      (oz == 0) o0 = fmaf(l, W0, fmaf(m, W1, fmaf(r, W2, o0)));
                    else if (oz == 1) o1 = fmaf(l, W0, fmaf(m, W1, fmaf(r, W2, o1)));
                    else if (oz == 2) o2 = fmaf(l, W0, fmaf(m, W1, fmaf(r, W2, o2)));
                    else              o3 = fmaf(l, W0, fmaf(m, W1, fmaf(r, W2, o3)));
                }
            }
        }
        float ps = (o0 + o1) + (o2 + o3);
        float pq = fmaf(o0, o0, fmaf(o1, o1, fmaf(o2, o2, o3 * o3)));
#pragma unroll
        for (int mm = 1; mm < 64; mm <<= 1) {
            ps += __shfl_xor(ps, mm, 64);
            pq += __shfl_xor(pq, mm, 64);
        }
        if (lane == 0) { red[0][c][wid] = ps; red[1][c][wid] = pq; }
    }
    __syncthreads();
    if (tid < 64) {
        const int c = tid & 31, st = tid >> 5;
        const float v = red[st][c][0] + red[st][c][1] + red[st][c][2] + red[st][c][3];
        atomicAdd(&acc[4 + st * 32 + c], v);
    }
}

// ---------------- Kernel 4: finalize bn2 -> per-channel scale/shift
__global__ void k_fin2(const float* __restrict__ g, const float* __restrict__ be,
                       float* __restrict__ acc)
{
    int c = threadIdx.x;                  // 32 threads
    float mean = acc[4 + c] * (1.0f / TS);
    float var  = acc[36 + c] * (1.0f / TS) - mean * mean;
    float sc = g[c] * rsqrtf(var + 1e-5f);
    acc[68 + c]  = sc;
    acc[100 + c] = be[c] - mean * sc;
}

// ---------------- Kernel 5: conv2 WRITE pass — recompute + bn2 affine + store.
// z x2 per thread; only 128 MiB of out traffic (single write).
__global__ __launch_bounds__(256) void k_conv2_write(
    const float* __restrict__ fuzz, const float* __restrict__ w2,
    const float* __restrict__ b2, const float* __restrict__ acc,
    float* __restrict__ out)
{
    const int tid = threadIdx.x;
    const int t = blockIdx.x * 256 + tid;        // 524288 threads
    const int lane = tid & 63;
    const int w = t & 63;                        // == lane
    const int y = (t >> 6) & 63;
    const int z0 = ((t >> 12) & 31) << 1;
    const int b = t >> 17;
    const float a = acc[2], sh = acc[3];
    const float* fb = fuzz + (size_t)b * SP;

    float Fl[4][3], Fm[4][3], Fr[4][3];
#pragma unroll
    for (int rz = 0; rz < 4; rz++) {
        const int zz = z0 - 1 + rz;
        const bool okz = (unsigned)zz < 64u;
#pragma unroll
        for (int dy = 0; dy < 3; dy++) {
            const int yy = y - 1 + dy;
            float f = 0.f;
            if (okz && (unsigned)yy < 64u)
                f = fmaf(a, fb[(zz << 12) + (yy << 6) + w], sh);
            const float lv = __shfl(f, (lane + 63) & 63, 64);
            const float rv = __shfl(f, (lane + 1) & 63, 64);
            Fm[rz][dy] = f;
            Fl[rz][dy] = (w > 0)  ? lv : 0.f;
            Fr[rz][dy] = (w < 63) ? rv : 0.f;
        }
    }

    float* ob = out + (size_t)b * Cc * SP + (z0 << 12) + (y << 6) + w;
#pragma unroll
    for (int c = 0; c < Cc; c++) {
        const float* wc = w2 + c * 27;
        float Wv[27];
#pragma unroll
        for (int k = 0; k < 27; k++) Wv[k] = wc[k];
        const float bb = b2[c];
        float o0 = bb, o1 = bb;
#pragma unroll
        for (int rz = 0; rz < 4; rz++) {
#pragma unroll
            for (int dy = 0; dy < 3; dy++) {
                const float l = Fl[rz][dy], m = Fm[rz][dy], r = Fr[rz][dy];
#pragma unroll
                for (int oz = 0; oz < 2; oz++) {
                    const int dz = rz - oz;
                    if (dz < 0 || dz > 2) continue;
                    const float W0 = Wv[(dz*3+dy)*3], W1 = Wv[(dz*3+dy)*3+1], W2 = Wv[(dz*3+dy)*3+2];
                    if (oz == 0) o0 = fmaf(l, W0, fmaf(m, W1, fmaf(r, W2, o0)));
                    else         o1 = fmaf(l, W0, fmaf(m, W1, fmaf(r, W2, o1)));
                }
            }
        }
        const float sc = acc[68 + c], shf = acc[100 + c];
        ob[(size_t)c * SP]        = fmaf(o0, sc, shf);
        ob[(size_t)c * SP + 4096] = fmaf(o1, sc, shf);
    }
}

extern "C" void kernel_launch(void* const* d_in, const int* in_sizes, int n_in,
                              void* d_out, int out_size, void* d_ws, size_t ws_size,
                              hipStream_t stream)
{
    const float* x   = (const float*)d_in[0];
    const float* w1  = (const float*)d_in[1];
    const float* b1  = (const float*)d_in[2];
    const float* w2  = (const float*)d_in[3];
    const float* b2  = (const float*)d_in[4];
    const float* mu  = (const float*)d_in[5];
    const float* sg  = (const float*)d_in[6];
    const float* g1  = (const float*)d_in[7];
    const float* be1 = (const float*)d_in[8];
    const float* g2  = (const float*)d_in[9];
    const float* be2 = (const float*)d_in[10];

    float* out  = (float*)d_out;
    float* fuzz = (float*)d_ws;
    float* acc  = fuzz + TS;

    hipMemsetAsync(acc, 0, 132 * sizeof(float), stream);
    k_conv1_fuzzy<<<512, 256, 0, stream>>>(x, w1, b1, mu, sg, fuzz, acc);
    k_fin1<<<1, 1, 0, stream>>>(g1, be1, acc);
    k_conv2_stats<<<1024, 256, 0, stream>>>(fuzz, w2, b2, acc);
    k_fin2<<<1, 32, 0, stream>>>(g2, be2, acc);
    k_conv2_write<<<2048, 256, 0, stream>>>(fuzz, w2, b2, acc, out);
}